// Round 11
// baseline (266.722 us; speedup 1.0000x reference)
//
#include <hip/hip_runtime.h>
#include <stdint.h>

typedef int v4i __attribute__((ext_vector_type(4)));
typedef float float4_t __attribute__((ext_vector_type(4)));

#define K_DIM 1024
#define N_DIM 1024
#define TOK 64  // tokens per block

__device__ __forceinline__ void gload16(const void* g, void* l) {
  __builtin_amdgcn_global_load_lds(
      (const __attribute__((address_space(1))) unsigned int*)g,
      (__attribute__((address_space(3))) unsigned int*)l, 16, 0, 0);
}

#define MFMA_I8 __builtin_amdgcn_mfma_i32_16x16x64_i8

// ---------------------------------------------------------------------------
// Kernel 1: per-row ternary weight quantization. 1 wave per row. (unchanged)
// ---------------------------------------------------------------------------
__global__ __launch_bounds__(256) void wquant_kernel(
    const float* __restrict__ w, int8_t* __restrict__ qw,
    float* __restrict__ wscale) {
  const int lane = threadIdx.x & 63;
  const int wid = threadIdx.x >> 6;
  const int row = blockIdx.x * 4 + wid;
  const float* wr = w + (long)row * K_DIM;

  float v[16];
  float s = 0.f;
  const float4_t* wr4 = (const float4_t*)wr;
#pragma unroll
  for (int rr = 0; rr < 4; ++rr) {
    float4_t f = wr4[rr * 64 + lane];
#pragma unroll
    for (int c = 0; c < 4; ++c) {
      v[rr * 4 + c] = f[c];
      s += fabsf(f[c]);
    }
  }
#pragma unroll
  for (int m = 32; m >= 1; m >>= 1) s += __shfl_xor(s, m, 64);
  const float scale = fmaxf(s * (1.0f / 1024.0f), 1e-5f);
  if (lane == 0) wscale[row] = scale;

  int8_t* qr = qw + (long)row * K_DIM;
#pragma unroll
  for (int rr = 0; rr < 4; ++rr) {
    int packed = 0;
#pragma unroll
    for (int c = 0; c < 4; ++c) {
      float n = v[rr * 4 + c] / scale;
      int tv = (n > 0.5f) ? 1 : ((n < -0.5f) ? -1 : 0);
      packed |= (tv & 0xff) << (8 * c);
    }
    *(int*)(qr + rr * 256 + lane * 4) = packed;
  }
}

// ---------------------------------------------------------------------------
// Kernel 2 (FUSED): per-block FWHT+quant of 64 tokens into LDS A-tile, then
// bn-loop GEMM against qw streamed from L2, LDS-transpose epilogue per bn.
// - FWHT identical arithmetic to R8 (bit-exact): e = lane*16+r mapping,
//   sign-FMA butterflies, scale = max(|.|)/32/7 folded.
// - A-tile [64][1024] i8 in LDS, per-kt-slice chunk-XOR swizzle written via
//   ds_write_b128 (reg-staged -> free swizzle; conflict-free: lanes cover
//   the full 1024B row contiguously per 16-lane phase).
// - B: 2x16KB gload_lds dbuf (linear dest + inverse-swizzled global src,
//   rule #21), staged 1 slice ahead, __syncthreads per slice.
// - Epilogue per bn: deposit 64x128 scaled f32 into tr (stride 132, 2-way),
//   sync, 4 full-line float4 nt stores/thread. acc reset per bn.
// - LDS 130 KB -> 1 block/CU; 1024 blocks = 4 generations.
// ---------------------------------------------------------------------------
__global__ __launch_bounds__(512) void fused_fwht_gemm_kernel(
    const float* __restrict__ x, const int8_t* __restrict__ Bq,
    const float* __restrict__ wsc, float* __restrict__ C) {
  __shared__ __align__(16) int8_t smem[132352];
  int8_t* At = smem;                        // [64][1024]   65536 B
  int8_t* Bb0 = smem + 65536;               // [128][128]   16384 B
  int8_t* Bb1 = smem + 81920;               // [128][128]   16384 B
  float* tr = (float*)(smem + 98304);       // [64][132]    33792 B
  float* ascl = (float*)(smem + 132096);    // [64]           256 B

  const int t = threadIdx.x;   // 0..511
  const int lane = t & 63;
  const int wid = t >> 6;      // 0..7
  const int wm = wid >> 2;     // 0..1  (32-row half)
  const int wn = wid & 3;      // 0..3  (32-col quarter)
  const int rl = lane & 15;
  const int kb = lane >> 4;
  const long bm = blockIdx.x;  // 0..M/64-1

  // ---------------- phase 1: FWHT + quant -> At ----------------
  {
    const float4_t* xb = (const float4_t*)(x + bm * TOK * (long)K_DIM);
    int token = wid * 8;  // 8 tokens per wave
    float4_t f0 = xb[(long)token * 256 + lane * 4 + 0];
    float4_t f1 = xb[(long)token * 256 + lane * 4 + 1];
    float4_t f2 = xb[(long)token * 256 + lane * 4 + 2];
    float4_t f3 = xb[(long)token * 256 + lane * 4 + 3];
    for (int tk = 0; tk < 8; ++tk) {
      float4_t g0, g1, g2, g3;
      if (tk < 7) {  // 1-deep prefetch of next token
        g0 = xb[(long)(token + 1) * 256 + lane * 4 + 0];
        g1 = xb[(long)(token + 1) * 256 + lane * 4 + 1];
        g2 = xb[(long)(token + 1) * 256 + lane * 4 + 2];
        g3 = xb[(long)(token + 1) * 256 + lane * 4 + 3];
      }
      float v[16];
#pragma unroll
      for (int c = 0; c < 4; ++c) {
        v[c] = f0[c]; v[4 + c] = f1[c]; v[8 + c] = f2[c]; v[12 + c] = f3[c];
      }
      // local stages: element strides 1,2,4,8
#pragma unroll
      for (int s = 1; s <= 8; s <<= 1) {
#pragma unroll
        for (int r = 0; r < 16; ++r)
          if ((r & s) == 0) {
            float a0 = v[r], b0 = v[r | s];
            v[r] = a0 + b0;
            v[r | s] = a0 - b0;
          }
      }
      // cross-lane stages: lane masks 1..32 (sign-FMA, exact)
#pragma unroll
      for (int m = 1; m <= 32; m <<= 1) {
        const float sg = (lane & m) ? -1.0f : 1.0f;
#pragma unroll
        for (int r = 0; r < 16; ++r) {
          float p = __shfl_xor(v[r], m, 64);
          v[r] = fmaf(sg, v[r], p);
        }
      }
      float mx = 0.f;
#pragma unroll
      for (int r = 0; r < 16; ++r) mx = fmaxf(mx, fabsf(v[r]));
#pragma unroll
      for (int m = 32; m >= 1; m >>= 1) mx = fmaxf(mx, __shfl_xor(mx, m, 64));
      const float scale = fmaxf(mx * 0.03125f, 1e-5f) * (1.0f / 7.0f);
      if (lane == 0) ascl[token] = scale;
      const float inv = 0.03125f / scale;

      v4i pk;
#pragma unroll
      for (int i = 0; i < 4; ++i) {
        int packed = 0;
#pragma unroll
        for (int c = 0; c < 4; ++c) {
          float q = rintf(v[i * 4 + c] * inv);
          q = fminf(7.f, fmaxf(-8.f, q));
          packed |= ((int)q & 0xff) << (8 * c);
        }
        pk[i] = packed;
      }
      // lane holds logical 16B-chunk `lane` of row `token`; kt-slice chunk-XOR
      *(v4i*)(At + token * 1024 + ((lane >> 3) << 7) +
              (((lane & 7) ^ (token & 7)) << 4)) = pk;
      f0 = g0; f1 = g1; f2 = g2; f3 = g3;
      ++token;
    }
  }

  // ---------------- phase 2: GEMM over bn x kt (64 slices) ----------------
  const int chunkoff = (((t & 7) ^ ((t >> 3) & 7)) << 4);
  const int sw0 = ((kb ^ (rl & 7)) << 4);
  const int sw1 = (((4 + kb) ^ (rl & 7)) << 4);
  const int arow0 = wm * 32 + rl;
  const int bcol0 = wn * 32 + rl;

  v4i acc[2][2] = {};

#define STAGE(s_)                                                             \
  {                                                                           \
    const int bn_ = (s_) >> 3, kt_ = (s_) & 7;                                \
    int8_t* dst = ((s_) & 1) ? Bb1 : Bb0;                                     \
    const int8_t* gB = Bq + ((long)(bn_ * 128 + (t >> 3))) * K_DIM +          \
                       kt_ * 128 + chunkoff;                                  \
    gload16(gB, dst + t * 16);                                                \
    gload16(gB + 64 * K_DIM, dst + 8192 + t * 16);                            \
  }

  STAGE(0);
  __syncthreads();  // At writes + B slice 0 visible

  for (int s = 0; s < 64; ++s) {
    const int kt = s & 7;
    if (s < 63) STAGE(s + 1);
    const int8_t* Bl = (s & 1) ? Bb1 : Bb0;
    v4i a[2][2], b[2][2];
#pragma unroll
    for (int i = 0; i < 2; ++i) {
      a[i][0] = *(const v4i*)(At + (arow0 + i * 16) * 1024 + kt * 128 + sw0);
      a[i][1] = *(const v4i*)(At + (arow0 + i * 16) * 1024 + kt * 128 + sw1);
    }
#pragma unroll
    for (int j = 0; j < 2; ++j) {
      b[j][0] = *(const v4i*)(Bl + (bcol0 + j * 16) * 128 + sw0);
      b[j][1] = *(const v4i*)(Bl + (bcol0 + j * 16) * 128 + sw1);
    }
#pragma unroll
    for (int i = 0; i < 2; ++i)
#pragma unroll
      for (int j = 0; j < 2; ++j) {
        acc[i][j] = MFMA_I8(a[i][0], b[j][0], acc[i][j], 0, 0, 0);
        acc[i][j] = MFMA_I8(a[i][1], b[j][1], acc[i][j], 0, 0, 0);
      }
    __syncthreads();  // slice s+1 landed; buf s reusable; MFMA inputs retired

    if (kt == 7) {
      const int bn = s >> 3;
      // deposit scaled acc into tr (all 8 waves, disjoint 64x128 coverage)
#pragma unroll
      for (int i = 0; i < 2; ++i) {
        float as[4];
#pragma unroll
        for (int r = 0; r < 4; ++r) as[r] = ascl[wm * 32 + i * 16 + kb * 4 + r];
#pragma unroll
        for (int j = 0; j < 2; ++j) {
          const float ws = wsc[bn * 128 + wn * 32 + j * 16 + rl];
#pragma unroll
          for (int r = 0; r < 4; ++r)
            tr[(wm * 32 + i * 16 + kb * 4 + r) * 132 + wn * 32 + j * 16 + rl] =
                (float)acc[i][j][r] * as[r] * ws;
        }
      }
      __syncthreads();
      // 512 thr x 4 float4 nt stores: 32 lanes cover 512B = 4 full lines
#pragma unroll
      for (int it = 0; it < 4; ++it) {
        const int idx = t + it * 512;   // 0..2047
        const int row = idx >> 5;       // 0..63
        const int c4 = (idx & 31) * 4;  // 0..124
        __builtin_nontemporal_store(
            *(const float4_t*)(tr + row * 132 + c4),
            (float4_t*)(C + (bm * TOK + row) * (long)N_DIM + bn * 128 + c4));
      }
      // no extra sync: next deposit is 8 kt-barriers away
#pragma unroll
      for (int i = 0; i < 2; ++i)
#pragma unroll
        for (int j = 0; j < 2; ++j) acc[i][j] = (v4i){0, 0, 0, 0};
    }
  }
#undef STAGE
}

// ---------------------------------------------------------------------------
extern "C" void kernel_launch(void* const* d_in, const int* in_sizes, int n_in,
                              void* d_out, int out_size, void* d_ws, size_t ws_size,
                              hipStream_t stream) {
  const float* x = (const float*)d_in[0];  // [8,8192,1024] f32
  const float* w = (const float*)d_in[1];  // [1024,1024] f32
  float* out = (float*)d_out;              // [8,8192,1024] f32
  const int M = in_sizes[0] / K_DIM;       // 65536

  // workspace: qw (N*K i8) | wscale (N f32)
  int8_t* qw = (int8_t*)d_ws;
  float* wscale = (float*)(qw + (size_t)N_DIM * K_DIM);

  wquant_kernel<<<N_DIM / 4, 256, 0, stream>>>(w, qw, wscale);
  fused_fwht_gemm_kernel<<<M / TOK, 512, 0, stream>>>(x, qw, wscale, out);
}

// Round 12
// 167.351 us; speedup vs baseline: 1.5938x; 1.5938x over previous
//
#include <hip/hip_runtime.h>
#include <stdint.h>

typedef int v4i __attribute__((ext_vector_type(4)));
typedef float float4_t __attribute__((ext_vector_type(4)));

#define K_DIM 1024
#define N_DIM 1024
#define BM 128
#define BN 128

__device__ __forceinline__ void gload16(const void* g, void* l) {
  __builtin_amdgcn_global_load_lds(
      (const __attribute__((address_space(1))) unsigned int*)g,
      (__attribute__((address_space(3))) unsigned int*)l, 16, 0, 0);
}

#define MFMA_I8 __builtin_amdgcn_mfma_i32_16x16x64_i8

// LDS-only barrier: orders DS ops across the workgroup WITHOUT draining the
// vmem (nontemporal-store) queue like __syncthreads does.
#define BAR_LDS()                                             \
  do {                                                        \
    asm volatile("s_waitcnt lgkmcnt(0)" ::: "memory");        \
    __builtin_amdgcn_s_barrier();                             \
  } while (0)

// ---------------------------------------------------------------------------
// Kernel 1: per-token FWHT (== x @ H, H = Sylvester/sqrt(1024)) + 4-bit quant.
// 1 wave/token, 16 f32/lane, mapping e = lane*16 + r. (unchanged from R8)
// ---------------------------------------------------------------------------
__global__ __launch_bounds__(256) void fwht_quant_kernel(
    const float* __restrict__ x, int8_t* __restrict__ qx,
    float* __restrict__ ascale, int M) {
  const int lane = threadIdx.x & 63;
  const int wid = threadIdx.x >> 6;
  const long token = (long)blockIdx.x * 4 + wid;
  if (token >= M) return;
  const float4_t* xr4 = (const float4_t*)(x + token * K_DIM);

  float v[16];
#pragma unroll
  for (int i = 0; i < 4; ++i) {
    float4_t f = xr4[lane * 4 + i];
#pragma unroll
    for (int c = 0; c < 4; ++c) v[i * 4 + c] = f[c];
  }
#pragma unroll
  for (int s = 1; s <= 8; s <<= 1) {
#pragma unroll
    for (int r = 0; r < 16; ++r)
      if ((r & s) == 0) {
        float a0 = v[r], b0 = v[r | s];
        v[r] = a0 + b0;
        v[r | s] = a0 - b0;
      }
  }
#pragma unroll
  for (int m = 1; m <= 32; m <<= 1) {
    const float sg = (lane & m) ? -1.0f : 1.0f;
#pragma unroll
    for (int r = 0; r < 16; ++r) {
      float p = __shfl_xor(v[r], m, 64);
      v[r] = fmaf(sg, v[r], p);
    }
  }
  float mx = 0.f;
#pragma unroll
  for (int r = 0; r < 16; ++r) mx = fmaxf(mx, fabsf(v[r]));
#pragma unroll
  for (int m = 32; m >= 1; m >>= 1) mx = fmaxf(mx, __shfl_xor(mx, m, 64));
  const float scale = fmaxf(mx * 0.03125f, 1e-5f) * (1.0f / 7.0f);
  if (lane == 0) ascale[token] = scale;
  const float inv = 0.03125f / scale;

  v4i pk;
#pragma unroll
  for (int i = 0; i < 4; ++i) {
    int packed = 0;
#pragma unroll
    for (int c = 0; c < 4; ++c) {
      float q = rintf(v[i * 4 + c] * inv);
      q = fminf(7.f, fmaxf(-8.f, q));
      packed |= ((int)q & 0xff) << (8 * c);
    }
    pk[i] = packed;
  }
  *(v4i*)(qx + token * K_DIM + lane * 16) = pk;
}

// ---------------------------------------------------------------------------
// Kernel 2: per-row ternary weight quantization. 1 wave per row. (unchanged)
// ---------------------------------------------------------------------------
__global__ __launch_bounds__(256) void wquant_kernel(
    const float* __restrict__ w, int8_t* __restrict__ qw,
    float* __restrict__ wscale) {
  const int lane = threadIdx.x & 63;
  const int wid = threadIdx.x >> 6;
  const int row = blockIdx.x * 4 + wid;
  const float* wr = w + (long)row * K_DIM;

  float v[16];
  float s = 0.f;
  const float4_t* wr4 = (const float4_t*)wr;
#pragma unroll
  for (int rr = 0; rr < 4; ++rr) {
    float4_t f = wr4[rr * 64 + lane];
#pragma unroll
    for (int c = 0; c < 4; ++c) {
      v[rr * 4 + c] = f[c];
      s += fabsf(f[c]);
    }
  }
#pragma unroll
  for (int m = 32; m >= 1; m >>= 1) s += __shfl_xor(s, m, 64);
  const float scale = fmaxf(s * (1.0f / 1024.0f), 1e-5f);
  if (lane == 0) wscale[row] = scale;

  int8_t* qr = qw + (long)row * K_DIM;
#pragma unroll
  for (int rr = 0; rr < 4; ++rr) {
    int packed = 0;
#pragma unroll
    for (int c = 0; c < 4; ++c) {
      float n = v[rr * 4 + c] / scale;
      int tv = (n > 0.5f) ? 1 : ((n < -0.5f) ? -1 : 0);
      packed |= (tv & 0xff) << (8 * c);
    }
    *(int*)(qr + rr * 256 + lane * 4) = packed;
  }
}

// ---------------------------------------------------------------------------
// Kernel 3: int8 GEMM = R8 verbatim (best measured) except ONE change:
// the epilogue's __syncthreads (which lowers to s_waitcnt vmcnt(0)+barrier,
// draining the nt-store queue to HBM twice per block) are replaced with
// LDS-only barriers (lgkmcnt(0)+s_barrier). The nt stores stay in flight
// across chunks and into the next block -> the HBM write path pipelines.
// Kept: 2-phase dbuf K-loop, T1 XCD swizzle, chunk-XOR LDS (verified
// uniform 8 dwords/bank = conflict-free), LDS-transpose epilogue with
// full-line float4 nt stores, tr stride 132.
// ---------------------------------------------------------------------------
__global__ __launch_bounds__(256) void gemm_i8_kernel(
    const int8_t* __restrict__ A, const int8_t* __restrict__ B,
    const float* __restrict__ asc, const float* __restrict__ wsc,
    float* __restrict__ C, int M) {
  __shared__ __align__(16) int8_t smem[2][32768];  // [p]: A 16KB | B 16KB
  float* tr = (float*)smem;  // epilogue: 64 rows x 132 f32 = 33792 B

  const int t = threadIdx.x;
  const int lane = t & 63;
  const int wm = (t >> 6) >> 1;
  const int wn = (t >> 6) & 1;
  const int rl = lane & 15;
  const int kb = lane >> 4;

  // T1: XCD swizzle. grid=4096 (%8==0): bm chunk per XCD, bn fastest.
  const int swz = ((int)blockIdx.x & 7) * 512 + ((int)blockIdx.x >> 3);
  const long bm = swz >> 3;  // 0..511
  const int bn = swz & 7;    // 0..7

  const int chunkoff = (((t & 7) ^ ((t >> 3) & 7)) << 4);
  const int8_t* gA = A + (bm * BM + (t >> 3)) * (long)K_DIM + chunkoff;
  const int8_t* gB = B + ((long)bn * BN + (t >> 3)) * K_DIM + chunkoff;

  const int sw0 = ((kb ^ (rl & 7)) << 4);
  const int sw1 = (((4 + kb) ^ (rl & 7)) << 4);
  const int arow = (wm * 64 + rl) * 128;
  const int brow = (wn * 64 + rl) * 128;

  v4i acc[4][4] = {};

#define STAGE(p, ks)                                         \
  gload16(gA + (ks), smem[p] + t * 16);                      \
  gload16(gA + (ks) + 32 * K_DIM, smem[p] + 4096 + t * 16);  \
  gload16(gA + (ks) + 64 * K_DIM, smem[p] + 8192 + t * 16);  \
  gload16(gA + (ks) + 96 * K_DIM, smem[p] + 12288 + t * 16); \
  gload16(gB + (ks), smem[p] + 16384 + t * 16);              \
  gload16(gB + (ks) + 32 * K_DIM, smem[p] + 20480 + t * 16); \
  gload16(gB + (ks) + 64 * K_DIM, smem[p] + 24576 + t * 16); \
  gload16(gB + (ks) + 96 * K_DIM, smem[p] + 28672 + t * 16);

  STAGE(0, 0);
  __syncthreads();

#pragma unroll
  for (int kt = 0; kt < 8; ++kt) {
    const int p = kt & 1;
    if (kt < 7) {
      STAGE(p ^ 1, (kt + 1) * 128);  // prefetch next tile under this compute
    }
    const int8_t* Al = smem[p];
    const int8_t* Bl = smem[p] + 16384;
#pragma unroll
    for (int ks2 = 0; ks2 < 2; ++ks2) {
      const int sw = ks2 ? sw1 : sw0;
      v4i a[4], b[4];
#pragma unroll
      for (int i = 0; i < 4; ++i)
        a[i] = *(const v4i*)(Al + arow + i * 2048 + sw);
#pragma unroll
      for (int j = 0; j < 4; ++j)
        b[j] = *(const v4i*)(Bl + brow + j * 2048 + sw);
#pragma unroll
      for (int i = 0; i < 4; ++i)
#pragma unroll
        for (int j = 0; j < 4; ++j)
          acc[i][j] = MFMA_I8(a[i], b[j], acc[i][j], 0, 0, 0);
    }
    __syncthreads();  // next tile landed; this tile's reads retired
  }
#undef STAGE

  // ---- LDS-transpose epilogue, 2 chunks of 64 rows, tr stride 132 ----
  // Barriers are LDS-only: nt stores never drain mid-kernel.
  const long rowg0 = bm * BM + wm * 64;
  const int colg0 = bn * BN + wn * 64;
#pragma unroll
  for (int c = 0; c < 2; ++c) {
    if (wm == c) {
#pragma unroll
      for (int i = 0; i < 4; ++i) {
        float as[4];
#pragma unroll
        for (int r = 0; r < 4; ++r) as[r] = asc[rowg0 + i * 16 + kb * 4 + r];
#pragma unroll
        for (int j = 0; j < 4; ++j) {
          const float ws = wsc[colg0 + j * 16 + rl];
#pragma unroll
          for (int r = 0; r < 4; ++r)
            tr[(i * 16 + kb * 4 + r) * 132 + wn * 64 + j * 16 + rl] =
                (float)acc[i][j][r] * as[r] * ws;
        }
      }
    }
    BAR_LDS();  // deposits visible; does NOT drain nt stores
    // 256 threads x 8 float4 nt stores: 32 lanes cover 512B = 4 full lines
#pragma unroll
    for (int it = 0; it < 8; ++it) {
      const int idx = t + it * 256;   // 0..2047
      const int rl2 = idx >> 5;       // local row 0..63
      const int c4 = (idx & 31) * 4;  // col in floats
      const float4_t val = *(const float4_t*)(tr + rl2 * 132 + c4);
      __builtin_nontemporal_store(
          val, (float4_t*)(C + (bm * BM + c * 64 + rl2) * (long)N_DIM + bn * BN + c4));
    }
    if (c == 0) BAR_LDS();  // tr ds_reads retired before re-deposit
  }
}

// ---------------------------------------------------------------------------
extern "C" void kernel_launch(void* const* d_in, const int* in_sizes, int n_in,
                              void* d_out, int out_size, void* d_ws, size_t ws_size,
                              hipStream_t stream) {
  const float* x = (const float*)d_in[0];  // [8,8192,1024] f32
  const float* w = (const float*)d_in[1];  // [1024,1024] f32
  float* out = (float*)d_out;              // [8,8192,1024] f32
  const int M = in_sizes[0] / K_DIM;       // 65536

  int8_t* qx = (int8_t*)d_ws;
  int8_t* qw = qx + (size_t)M * K_DIM;
  float* ascale = (float*)(qw + (size_t)N_DIM * K_DIM);
  float* wscale = ascale + M;

  fwht_quant_kernel<<<(M + 3) / 4, 256, 0, stream>>>(x, qx, ascale, M);
  wquant_kernel<<<N_DIM / 4, 256, 0, stream>>>(w, qw, wscale);
  gemm_i8_kernel<<<(M / BM) * (N_DIM / BN), 256, 0, stream>>>(qx, qw, ascale, wscale, out, M);
}